// Round 1
// baseline (94.358 us; speedup 1.0000x reference)
//
#include <hip/hip_runtime.h>

#define NSLOPE 0.01f

// One thread per non-overlapping 2^4 spatial block.
// B=4, D=32 -> 4 * 16^4 = 262144 threads = 1024 blocks of 256.
__global__ __launch_bounds__(256) void fused_conv4d_kernel(
    const float* __restrict__ x,
    const float* __restrict__ w0,
    const float* __restrict__ b0,
    const float* __restrict__ w1,
    const float* __restrict__ b1,
    const float* __restrict__ wt,
    const float* __restrict__ bt,
    float* __restrict__ out)
{
    // Transposed weight staging in LDS, padded to 8 floats/group for aligned
    // float4+float2 broadcast reads.
    //   lw1[(c*16+j)*8 + o]  from w1 flat [o*48 + c*16 + j]
    //   lwt[(o*16+j)*8 + i]  from wt flat [i*48 + o*16 + j]
    __shared__ float lw1[48 * 8];
    __shared__ float lwt[48 * 8];
    for (int k = threadIdx.x; k < 288; k += 256) {
        int o   = k / 48;          // leading index (o for w1, i for wt)
        int rem = k - o * 48;      // (c*16+j) for w1, (o*16+j) for wt
        lw1[rem * 8 + o] = w1[k];
        lwt[rem * 8 + o] = wt[k];
    }
    __syncthreads();

    int tid = blockIdx.x * 256 + threadIdx.x;
    int b   = tid >> 16;
    int rem = tid & 65535;
    int d   = (rem >> 12) & 15;
    int e   = (rem >> 8) & 15;
    int f   = (rem >> 4) & 15;
    int g   = rem & 15;

    // x flat: [b][0][a1][a2][a3][a4], strides 1048576 / 32768 / 1024 / 32 / 1
    int xbase = b * 1048576 + d * 65536 + e * 2048 + f * 64 + g * 2;

    // Load the 16 block inputs (8 x float2, each wave-instr = 4 full 128B lines)
    float xv[16];
    #pragma unroll
    for (int p = 0; p < 2; ++p)
    #pragma unroll
    for (int q = 0; q < 2; ++q)
    #pragma unroll
    for (int r = 0; r < 2; ++r) {
        float2 v = *(const float2*)(x + xbase + p * 32768 + q * 1024 + r * 32);
        int j = p * 8 + q * 4 + r * 2;
        xv[j]     = v.x;
        xv[j + 1] = v.y;
    }

    // Small uniform params straight from global (L1 broadcast, hoisted)
    float W0[3], B0[3], B1[6], BT[3];
    #pragma unroll
    for (int c = 0; c < 3; ++c) { W0[c] = w0[c]; B0[c] = b0[c]; BT[c] = bt[c]; }
    #pragma unroll
    for (int i = 0; i < 6; ++i) B1[i] = b1[i];

    // Stage 1 + 2: y1[o2] = sum_{c,j} w1[o2,c,j] * lrelu(w0[c]*x[j] + b0[c])
    float y1[6] = {0.f, 0.f, 0.f, 0.f, 0.f, 0.f};
    #pragma unroll
    for (int j = 0; j < 16; ++j) {
        #pragma unroll
        for (int c = 0; c < 3; ++c) {
            float t = fmaf(W0[c], xv[j], B0[c]);
            t = t >= 0.0f ? t : NSLOPE * t;
            const float* wp = &lw1[(c * 16 + j) * 8];
            float4 wa = *(const float4*)wp;
            float2 wb = *(const float2*)(wp + 4);
            y1[0] = fmaf(wa.x, t, y1[0]);
            y1[1] = fmaf(wa.y, t, y1[1]);
            y1[2] = fmaf(wa.z, t, y1[2]);
            y1[3] = fmaf(wa.w, t, y1[3]);
            y1[4] = fmaf(wb.x, t, y1[4]);
            y1[5] = fmaf(wb.y, t, y1[5]);
        }
    }
    #pragma unroll
    for (int i = 0; i < 6; ++i) {
        float t = y1[i] + B1[i];
        y1[i] = t >= 0.0f ? t : NSLOPE * t;
    }

    // Stage 3: z[o][j] = sigmoid(sum_i wt[i,o,j]*y1[i] + bt[o])
    #pragma unroll
    for (int o = 0; o < 3; ++o) {
        int obase = (b * 3 + o) * 1048576 + d * 65536 + e * 2048 + f * 64 + g * 2;
        #pragma unroll
        for (int p = 0; p < 2; ++p)
        #pragma unroll
        for (int q = 0; q < 2; ++q)
        #pragma unroll
        for (int r = 0; r < 2; ++r) {
            float2 res;
            #pragma unroll
            for (int s = 0; s < 2; ++s) {
                int j = p * 8 + q * 4 + r * 2 + s;
                const float* wp = &lwt[(o * 16 + j) * 8];
                float4 wa = *(const float4*)wp;
                float2 wb = *(const float2*)(wp + 4);
                float acc = BT[o];
                acc = fmaf(wa.x, y1[0], acc);
                acc = fmaf(wa.y, y1[1], acc);
                acc = fmaf(wa.z, y1[2], acc);
                acc = fmaf(wa.w, y1[3], acc);
                acc = fmaf(wb.x, y1[4], acc);
                acc = fmaf(wb.y, y1[5], acc);
                float sg = __builtin_amdgcn_rcpf(1.0f + __expf(-acc));
                if (s == 0) res.x = sg; else res.y = sg;
            }
            *(float2*)(out + obase + p * 32768 + q * 1024 + r * 32) = res;
        }
    }
}

extern "C" void kernel_launch(void* const* d_in, const int* in_sizes, int n_in,
                              void* d_out, int out_size, void* d_ws, size_t ws_size,
                              hipStream_t stream) {
    const float* x  = (const float*)d_in[0];
    const float* w0 = (const float*)d_in[1];
    const float* b0 = (const float*)d_in[2];
    const float* w1 = (const float*)d_in[3];
    const float* b1 = (const float*)d_in[4];
    const float* wt = (const float*)d_in[5];
    const float* bt = (const float*)d_in[6];
    float* out = (float*)d_out;

    // 4 * 16^4 blocks, one thread each
    fused_conv4d_kernel<<<1024, 256, 0, stream>>>(x, w0, b0, w1, b1, wt, bt, out);
}

// Round 3
// 93.580 us; speedup vs baseline: 1.0083x; 1.0083x over previous
//
#include <hip/hip_runtime.h>

#define NSLOPE 0.01f

typedef float vfloat4 __attribute__((ext_vector_type(4)));

// Two adjacent non-overlapping 2^4 spatial blocks per thread (adjacent in the
// innermost axis), so every global access is a full float4 (16 B/lane).
// B=4, D=32 -> 4 * 16^3 * 8 = 131072 threads = 512 blocks of 256.
__global__ __launch_bounds__(256) void fused_conv4d_kernel(
    const float* __restrict__ x,
    const float* __restrict__ w0,
    const float* __restrict__ b0,
    const float* __restrict__ w1,
    const float* __restrict__ b1,
    const float* __restrict__ wt,
    const float* __restrict__ bt,
    float* __restrict__ out)
{
    // Transposed weight staging in LDS, padded to 8 floats/group for aligned
    // float4+float2 broadcast reads (same-address across wave -> conflict-free).
    //   lw1[(c*16+j)*8 + o]  from w1 flat [o*48 + c*16 + j]
    //   lwt[(o*16+j)*8 + i]  from wt flat [i*48 + o*16 + j]
    __shared__ float lw1[48 * 8];
    __shared__ float lwt[48 * 8];
    for (int k = threadIdx.x; k < 288; k += 256) {
        int o   = k / 48;
        int rem = k - o * 48;
        lw1[rem * 8 + o] = w1[k];
        lwt[rem * 8 + o] = wt[k];
    }
    __syncthreads();

    int tid = blockIdx.x * 256 + threadIdx.x;   // 0..131071
    int b   = tid >> 15;
    int rem = tid & 32767;
    int d   = (rem >> 11) & 15;
    int e   = (rem >> 7) & 15;
    int f   = (rem >> 3) & 15;
    int u   = rem & 7;                           // pair-of-blocks index along axis 4

    // x flat: [b][0][a1][a2][a3][a4], strides 1048576 / 32768 / 1024 / 32 / 1
    // This thread covers columns 4u..4u+3: block A = cols 4u,4u+1; block B = 4u+2,4u+3.
    int xbase = b * 1048576 + d * 65536 + e * 2048 + f * 64 + u * 4;

    float xa[16], xb[16];
    #pragma unroll
    for (int p = 0; p < 2; ++p)
    #pragma unroll
    for (int q = 0; q < 2; ++q)
    #pragma unroll
    for (int r = 0; r < 2; ++r) {
        float4 v = *(const float4*)(x + xbase + p * 32768 + q * 1024 + r * 32);
        int j = p * 8 + q * 4 + r * 2;
        xa[j] = v.x; xa[j + 1] = v.y;
        xb[j] = v.z; xb[j + 1] = v.w;
    }

    // Small uniform params (wave-uniform L1 broadcast)
    float W0[3], B0[3], B1[6], BT[3];
    #pragma unroll
    for (int c = 0; c < 3; ++c) { W0[c] = w0[c]; B0[c] = b0[c]; BT[c] = bt[c]; }
    #pragma unroll
    for (int i = 0; i < 6; ++i) B1[i] = b1[i];

    // Stage 1 + 2 for both blocks: y1[o2] = sum_{c,j} w1[o2,c,j]*lrelu(w0[c]*x[j]+b0[c])
    float y1a[6] = {0,0,0,0,0,0};
    float y1b[6] = {0,0,0,0,0,0};
    #pragma unroll
    for (int j = 0; j < 16; ++j) {
        #pragma unroll
        for (int c = 0; c < 3; ++c) {
            float ta = fmaf(W0[c], xa[j], B0[c]);
            ta = ta >= 0.0f ? ta : NSLOPE * ta;
            float tb = fmaf(W0[c], xb[j], B0[c]);
            tb = tb >= 0.0f ? tb : NSLOPE * tb;
            const float* wp = &lw1[(c * 16 + j) * 8];
            float4 wa = *(const float4*)wp;
            float2 wb = *(const float2*)(wp + 4);
            y1a[0] = fmaf(wa.x, ta, y1a[0]);  y1b[0] = fmaf(wa.x, tb, y1b[0]);
            y1a[1] = fmaf(wa.y, ta, y1a[1]);  y1b[1] = fmaf(wa.y, tb, y1b[1]);
            y1a[2] = fmaf(wa.z, ta, y1a[2]);  y1b[2] = fmaf(wa.z, tb, y1b[2]);
            y1a[3] = fmaf(wa.w, ta, y1a[3]);  y1b[3] = fmaf(wa.w, tb, y1b[3]);
            y1a[4] = fmaf(wb.x, ta, y1a[4]);  y1b[4] = fmaf(wb.x, tb, y1b[4]);
            y1a[5] = fmaf(wb.y, ta, y1a[5]);  y1b[5] = fmaf(wb.y, tb, y1b[5]);
        }
    }
    #pragma unroll
    for (int i = 0; i < 6; ++i) {
        float ta = y1a[i] + B1[i];
        y1a[i] = ta >= 0.0f ? ta : NSLOPE * ta;
        float tb = y1b[i] + B1[i];
        y1b[i] = tb >= 0.0f ? tb : NSLOPE * tb;
    }

    // Stage 3: z[o][j] = sigmoid(sum_i wt[i,o,j]*y1[i] + bt[o]); float4 stores.
    #pragma unroll
    for (int o = 0; o < 3; ++o) {
        int obase = (b * 3 + o) * 1048576 + d * 65536 + e * 2048 + f * 64 + u * 4;
        #pragma unroll
        for (int p = 0; p < 2; ++p)
        #pragma unroll
        for (int q = 0; q < 2; ++q)
        #pragma unroll
        for (int r = 0; r < 2; ++r) {
            int J = p * 8 + q * 4 + r * 2;
            vfloat4 res;
            #pragma unroll
            for (int s = 0; s < 2; ++s) {
                const float* wp = &lwt[(o * 16 + J + s) * 8];
                float4 wa = *(const float4*)wp;
                float2 wb = *(const float2*)(wp + 4);
                float acc_a = BT[o];
                acc_a = fmaf(wa.x, y1a[0], acc_a);
                acc_a = fmaf(wa.y, y1a[1], acc_a);
                acc_a = fmaf(wa.z, y1a[2], acc_a);
                acc_a = fmaf(wa.w, y1a[3], acc_a);
                acc_a = fmaf(wb.x, y1a[4], acc_a);
                acc_a = fmaf(wb.y, y1a[5], acc_a);
                float acc_b = BT[o];
                acc_b = fmaf(wa.x, y1b[0], acc_b);
                acc_b = fmaf(wa.y, y1b[1], acc_b);
                acc_b = fmaf(wa.z, y1b[2], acc_b);
                acc_b = fmaf(wa.w, y1b[3], acc_b);
                acc_b = fmaf(wb.x, y1b[4], acc_b);
                acc_b = fmaf(wb.y, y1b[5], acc_b);
                float sa = __builtin_amdgcn_rcpf(1.0f + __expf(-acc_a));
                float sb = __builtin_amdgcn_rcpf(1.0f + __expf(-acc_b));
                if (s == 0) { res.x = sa; res.z = sb; }
                else        { res.y = sa; res.w = sb; }
            }
            // write-once 50 MB stream: nontemporal to avoid cache pollution
            __builtin_nontemporal_store(res, (vfloat4*)(out + obase + p * 32768 + q * 1024 + r * 32));
        }
    }
}

extern "C" void kernel_launch(void* const* d_in, const int* in_sizes, int n_in,
                              void* d_out, int out_size, void* d_ws, size_t ws_size,
                              hipStream_t stream) {
    const float* x  = (const float*)d_in[0];
    const float* w0 = (const float*)d_in[1];
    const float* b0 = (const float*)d_in[2];
    const float* w1 = (const float*)d_in[3];
    const float* b1 = (const float*)d_in[4];
    const float* wt = (const float*)d_in[5];
    const float* bt = (const float*)d_in[6];
    float* out = (float*)d_out;

    fused_conv4d_kernel<<<512, 256, 0, stream>>>(x, w0, b0, w1, b1, wt, bt, out);
}